// Round 4
// baseline (8534.622 us; speedup 1.0000x reference)
//
#include <hip/hip_runtime.h>
#include <hip/hip_bf16.h>
#include <stdint.h>

#define NT 365
#define NGRID 512
#define NX 256
#define HID 1024

typedef __bf16 bf16x8 __attribute__((ext_vector_type(8)));
typedef float f32x16 __attribute__((ext_vector_type(16)));
typedef float f32x4  __attribute__((ext_vector_type(4)));
typedef int   i32x4  __attribute__((ext_vector_type(4)));

__device__ __forceinline__ unsigned short f2bf(float f) {
    union { float f; uint32_t u; } v; v.f = f;
    uint32_t u = v.u;
    uint32_t r = (u + 0x7FFFu + ((u >> 16) & 1u)) >> 16;
    return (unsigned short)r;
}
__device__ __forceinline__ float sigmoidf_(float x) {
    return 1.0f / (1.0f + __expf(-x));
}
__device__ __forceinline__ float tanhf_(float x) {
    return 1.0f - 2.0f / (__expf(2.0f * x) + 1.0f);
}
__device__ __forceinline__ f32x16 mfma(bf16x8 a, bf16x8 b, f32x16 c) {
    return __builtin_amdgcn_mfma_f32_32x32x16_bf16(a, b, c, 0, 0, 0);
}

// ---------------- prep kernels ----------------

// WP[jg 0..127][kt 0..79][l 0..63][e 0..7] : B-frag order, gate-packed cols.
__global__ void pack_w_kernel(const float* __restrict__ W_ih,
                              const float* __restrict__ W_hh,
                              unsigned short* __restrict__ WP) {
    int tid = blockIdx.x * blockDim.x + threadIdx.x;
    if (tid >= 128 * 80 * 64) return;
    int l  = tid & 63;
    int kt = (tid >> 6) % 80;
    int jg = tid / (80 * 64);
    int n = l & 31;
    int gate = n & 3;
    int j = jg * 8 + (n >> 2);
    int k = kt * 16 + ((l >> 5) << 3);
    int row = gate * HID + j;
    const float* src = (k < HID) ? (W_hh + (size_t)row * HID + k)
                                 : (W_ih + (size_t)row * NX + (k - HID));
    unsigned short* dst = WP + (size_t)tid * 8;
    #pragma unroll
    for (int e = 0; e < 8; ++e) dst[e] = f2bf(src[e]);
}

// XM[t][bi][kt 0..15][a][l][e] : A-frag order of bf16(x * maskX).
__global__ void pack_xm_kernel(const float* __restrict__ x,
                               const float* __restrict__ maskX,
                               unsigned short* __restrict__ XM) {
    size_t tid = (size_t)blockIdx.x * blockDim.x + threadIdx.x;
    if (tid >= (size_t)NT * 16384) return;
    int l  = tid & 63;
    int a  = (tid >> 6) & 1;
    int kt = (tid >> 7) & 15;
    int bi = (tid >> 11) & 7;
    int t  = tid >> 14;
    int b = bi * 64 + a * 32 + (l & 31);
    int n = kt * 16 + ((l >> 5) << 3);
    const float* xs = x + ((size_t)t * NGRID + b) * NX + n;
    const float* ms = maskX + (size_t)b * NX + n;
    unsigned short* dst = XM + tid * 8;
    #pragma unroll
    for (int e = 0; e < 8; ++e) dst[e] = f2bf(xs[e] * ms[e]);
}

__global__ void init_kernel(float* __restrict__ out,
                            const float* __restrict__ b_lin,
                            int* __restrict__ ctr, int prefill) {
    int i = blockIdx.x * blockDim.x + threadIdx.x;
    if (i < 1024) ctr[i] = 0;
    if (prefill && i < NT * NGRID) out[i] = b_lin[0];
}

// final reduction: out[t,b] = b_lin + sum_wgJ OPart[t][bi][wgJ][bl]
__global__ void reduce_out_kernel(const float* __restrict__ OPart,
                                  const float* __restrict__ b_lin,
                                  float* __restrict__ out) {
    int i = blockIdx.x * blockDim.x + threadIdx.x;
    if (i >= NT * NGRID) return;
    int t = i >> 9, b = i & 511;
    int bi = b >> 6, bl = b & 63;
    const float* p = OPart + ((size_t)(t * 8 + bi) * 32) * 64 + bl;
    float s = b_lin[0];
    #pragma unroll
    for (int g = 0; g < 32; ++g) s += p[g * 64];
    out[i] = s;
}

// ---------------- persistent LSTM loop (templated on exchange scope) ----------------
// K-SPLIT this round: wave pair (2p, 2p+1) shares TWO col-slices (sA, sA+1);
// each wave computes BOTH slices over HALF of K (hk = w&1 -> kt range hk*32..+32).
// Every LDS A-fragment read now feeds 4 MFMAs instead of 2, halving the dominant
// per-CU LDS read traffic (512 -> 256 KB/step). A small LDS merge recombines the
// k-halves; afterwards wave w owns slice jg = wgJ*4+w exactly as before, so the
// transpose/elementwise/store/output code is unchanged.
template<bool BAL>
__device__ void lstm_loop(int tid, int bi, int wgJ,
                          const unsigned short* __restrict__ WPg,
                          const unsigned short* __restrict__ XMg,
                          unsigned int* __restrict__ hA,
                          unsigned int* __restrict__ hB,
                          const float* __restrict__ b_ih,
                          const float* __restrict__ b_hh,
                          const float* __restrict__ W_lin,
                          float* __restrict__ out,
                          float* __restrict__ OPart,
                          int* __restrict__ flags,
                          i32x4* hsm4)
{
    const int w = tid >> 6;
    const int l = tid & 63;
    const int jg = wgJ * 4 + w;          // owned slice (post-merge)
    const int hk = w & 1;                // k-half of the pair
    const int sA = wgJ * 4 + (w & ~1);   // even slice of the pair

    float* exch = (float*)hsm4;                 // 4 x 2560 floats (overlay)
    float* outred = (float*)hsm4 + 10240;       // 256 floats (overlay)
    unsigned long long* hsm = (unsigned long long*)hsm4;

    // W resident: 2 slices x 32 kt (this wave's k-half) = 64 frags = 256 regs
    const bf16x8* __restrict__ WPvA = (const bf16x8*)WPg + (size_t)sA * 5120
                                      + (size_t)(hk * 32) * 64 + l;
    bf16x8 wregA[32], wregB[32];
    #pragma unroll
    for (int kt = 0; kt < 32; ++kt) {
        wregA[kt] = WPvA[kt * 64];
        wregB[kt] = WPvA[5120 + kt * 64];
    }
    // xm-part B-frags (streamed from L2), split by hk: kt_local = hk*8 + [0..8)
    const bf16x8* __restrict__ WPxA = (const bf16x8*)WPg + (size_t)sA * 5120
                                      + (size_t)(64 + hk * 8) * 64 + l;

    const int c = l & 31;
    const int gate = c & 3;
    const int jcol = jg * 8 + (c >> 2);
    const float bias = b_ih[gate * HID + jcol] + b_hh[gate * HID + jcol];

    const int p = l & 3;
    const int rl = l >> 2;
    const float wl0 = W_lin[jg * 8 + 2 * p];
    const float wl1 = W_lin[jg * 8 + 2 * p + 1];

    const bf16x8* __restrict__ XMv = (const bf16x8*)XMg;
    const int voff = tid * 16;

    const uint64_t flags64 = (uint64_t)(uintptr_t)flags;
    const uint64_t sig64   = (uint64_t)(uintptr_t)(flags + wgJ);

    float creg[8];
    #pragma unroll
    for (int k = 0; k < 8; ++k) creg[k] = 0.0f;

    f32x16 aA0, aA1, aB0, aB1;

    auto issue = [&](i32x4* stg, uint64_t base) {
        #pragma unroll
        for (int ch = 0; ch < 8; ++ch)
            asm volatile("global_load_dwordx4 %0, %1, %2 sc0"
                         : "=v"(stg[ch])
                         : "v"(voff), "s"(base + (uint64_t)(ch * 4096)));
    };
    auto lwrite = [&](const i32x4* stg, int reg) {
        #pragma unroll
        for (int ch = 0; ch < 8; ++ch) hsm4[reg * 2048 + ch * 256 + tid] = stg[ch];
    };
    // chunk cn covers kt range [cn*16, cn*16+16); only waves with hk == cn>>1
    // consume it, computing BOTH slices (A-frag reused x2).
    auto mchunk = [&](int reg, int cn) {
        if ((cn >> 1) != hk) return;
        const int kb = (cn & 1) * 16;
        const bf16x8* hls = (const bf16x8*)(hsm4 + reg * 2048);
        #pragma unroll
        for (int kt = 0; kt < 16; ++kt) {
            bf16x8 a0 = hls[kt * 128 + l];
            bf16x8 a1 = hls[kt * 128 + 64 + l];
            aA0 = mfma(a0, wregA[kb + kt], aA0);
            aA1 = mfma(a1, wregA[kb + kt], aA1);
            aB0 = mfma(a0, wregB[kb + kt], aB0);
            aB1 = mfma(a1, wregB[kb + kt], aB1);
        }
    };

    #pragma unroll 1
    for (int t = 0; t < NT; ++t) {
        aA0 = (f32x16){}; aA1 = (f32x16){};
        aB0 = (f32x16){}; aB1 = (f32x16){};

        // ---- xm part (k-half hk): plain cached loads, independent of the flag ----
        const bf16x8* __restrict__ xp = XMv + (size_t)t * 16384 + bi * 2048
                                        + (hk * 8) * 128 + l;
        #pragma unroll
        for (int kt = 0; kt < 8; ++kt) {
            bf16x8 x0 = xp[kt * 128];
            bf16x8 x1 = xp[kt * 128 + 64];
            bf16x8 bA = WPxA[kt * 64];
            bf16x8 bB = WPxA[5120 + kt * 64];
            aA0 = mfma(x0, bA, aA0);
            aA1 = mfma(x1, bA, aA1);
            aB0 = mfma(x0, bB, aB0);
            aB1 = mfma(x1, bB, aB1);
        }

        // ---- wait for h(t-1): read-only per-slot poll, lane i watches slot i ----
        if (t > 0 && tid < 32) {
            if constexpr (BAL) {
                while (true) {
                    int v;
                    asm volatile("global_load_dword %0, %1, %2 sc0\n\t"
                                 "s_waitcnt vmcnt(0)"
                                 : "=v"(v)
                                 : "v"(tid * 4), "s"(flags64)
                                 : "memory");
                    if (v >= t) break;
                }
            } else {
                while (__hip_atomic_load(flags + tid, __ATOMIC_RELAXED,
                                         __HIP_MEMORY_SCOPE_AGENT) < t)
                    __builtin_amdgcn_s_sleep(2);
            }
        }
        __syncthreads();   // (c)

        if (t > 0) {
            __asm__ volatile("" ::: "memory");
            const char* hb = (const char*)((t & 1) ? hA : hB) + (size_t)bi * 131072;

            if constexpr (BAL) {
                uint64_t hb64 = (uint64_t)(uintptr_t)hb;
                i32x4 s0[8], s1[8];
                issue(s0, hb64);             // c0
                issue(s1, hb64 + 32768);     // c1
                asm volatile("s_waitcnt vmcnt(8)" ::: "memory");   // c0 arrived
                lwrite(s0, 0); __syncthreads();
                issue(s0, hb64 + 65536);     // c2
                mchunk(0, 0);
                asm volatile("s_waitcnt vmcnt(8)" ::: "memory");   // c1 arrived
                lwrite(s1, 1); __syncthreads();
                issue(s1, hb64 + 98304);     // c3
                mchunk(1, 1);
                asm volatile("s_waitcnt vmcnt(8)" ::: "memory");   // c2 arrived
                lwrite(s0, 0); __syncthreads();
                mchunk(0, 2);
                asm volatile("s_waitcnt vmcnt(0)" ::: "memory");   // c3 arrived
                lwrite(s1, 1); __syncthreads();
                mchunk(1, 3);
                __syncthreads();   // all waves done reading before merge overlay
            } else {
                const unsigned long long* __restrict__ hr =
                    (const unsigned long long*)hb + tid;
                unsigned long long stg[16];
                #pragma unroll
                for (int ch = 0; ch < 16; ++ch)
                    stg[ch] = __hip_atomic_load(hr + ch * 256, __ATOMIC_RELAXED,
                                                __HIP_MEMORY_SCOPE_AGENT);
                #pragma unroll
                for (int ch = 0; ch < 16; ++ch) hsm[ch * 256 + tid] = stg[ch];
                __syncthreads();
                #pragma unroll
                for (int ci = 0; ci < 4; ++ci) {
                    if (ci < 3) {
                        #pragma unroll
                        for (int ch = 0; ch < 16; ++ch)
                            stg[ch] = __hip_atomic_load(hr + (ci + 1) * 4096 + ch * 256,
                                                        __ATOMIC_RELAXED,
                                                        __HIP_MEMORY_SCOPE_AGENT);
                    }
                    mchunk(ci & 1, ci);
                    if (ci < 3) {
                        unsigned long long* __restrict__ dst = hsm + ((ci + 1) & 1) * 4096;
                        #pragma unroll
                        for (int ch = 0; ch < 16; ++ch) dst[ch * 256 + tid] = stg[ch];
                    }
                    __syncthreads();
                }
            }
        }

        // ---- merge k-halves within the wave pair (via 32 KB LDS overlay) ----
        f32x16 acc0, acc1;
        {
            i32x4* mg = hsm4;
            const int ps = (w ^ 1) * 512;   // partner's slot (they own what I write)
            if (hk) {   // I own slice B; hand over my slice-A partials
                #pragma unroll
                for (int q = 0; q < 4; ++q) {
                    mg[ps + q * 64 + l]       = ((i32x4*)&aA0)[q];
                    mg[ps + 256 + q * 64 + l] = ((i32x4*)&aA1)[q];
                }
            } else {    // I own slice A; hand over my slice-B partials
                #pragma unroll
                for (int q = 0; q < 4; ++q) {
                    mg[ps + q * 64 + l]       = ((i32x4*)&aB0)[q];
                    mg[ps + 256 + q * 64 + l] = ((i32x4*)&aB1)[q];
                }
            }
            __syncthreads();
            const int ms = w * 512;
            if (hk) {
                #pragma unroll
                for (int q = 0; q < 4; ++q) {
                    i32x4 v0 = mg[ms + q * 64 + l];
                    i32x4 v1 = mg[ms + 256 + q * 64 + l];
                    ((f32x4*)&aB0)[q] += *(const f32x4*)&v0;
                    ((f32x4*)&aB1)[q] += *(const f32x4*)&v1;
                }
                acc0 = aB0; acc1 = aB1;
            } else {
                #pragma unroll
                for (int q = 0; q < 4; ++q) {
                    i32x4 v0 = mg[ms + q * 64 + l];
                    i32x4 v1 = mg[ms + 256 + q * 64 + l];
                    ((f32x4*)&aA0)[q] += *(const f32x4*)&v0;
                    ((f32x4*)&aA1)[q] += *(const f32x4*)&v1;
                }
                acc0 = aA0; acc1 = aA1;
            }
            __syncthreads();   // slots free before exch overlay
        }

        // ---- gate transpose through per-wave LDS ----
        const int jj = c >> 2;
        const int wb = w * 2560;
        #pragma unroll
        for (int ri = 0; ri < 16; ++ri) {
            int r0 = (ri & 3) + 8 * (ri >> 2) + 4 * (l >> 5);
            exch[wb + (r0 * 8 + jj) * 5 + gate]        = acc0[ri] + bias;
            exch[wb + ((r0 + 32) * 8 + jj) * 5 + gate] = acc1[ri] + bias;
        }

        unsigned int* __restrict__ hw =
            ((t & 1) ? hB : hA) + (size_t)bi * 32768 + (jg >> 1) * 512 + p;
        float pr[4];
        #pragma unroll
        for (int k = 0; k < 4; ++k) {
            int r = rl + 16 * k;
            int f0 = wb + (r * 8 + 2 * p) * 5;
            float ia = sigmoidf_(exch[f0 + 0]);
            float fa = sigmoidf_(exch[f0 + 1]);
            float ga = tanhf_(exch[f0 + 2]);
            float oa = sigmoidf_(exch[f0 + 3]);
            float ib = sigmoidf_(exch[f0 + 5]);
            float fb = sigmoidf_(exch[f0 + 6]);
            float gb = tanhf_(exch[f0 + 7]);
            float ob = sigmoidf_(exch[f0 + 8]);
            float c0 = fa * creg[2 * k] + ia * ga;     creg[2 * k] = c0;
            float c1 = fb * creg[2 * k + 1] + ib * gb; creg[2 * k + 1] = c1;
            float h0 = oa * tanhf_(c0);
            float h1 = ob * tanhf_(c1);
            unsigned int pk = (unsigned int)f2bf(h0) | ((unsigned int)f2bf(h1) << 16);
            int a = r >> 5;
            int flane = ((jg & 1) << 5) | (r & 31);
            if constexpr (BAL)
                hw[a * 256 + flane * 4] = pk;          // write-through L1 -> XCD L2
            else
                __hip_atomic_store(&hw[a * 256 + flane * 4], pk, __ATOMIC_RELAXED,
                                   __HIP_MEMORY_SCOPE_AGENT);
            pr[k] = h0 * wl0 + h1 * wl1;
        }

        // drain h stores to the coherence point, then SIGNAL EARLY
        asm volatile("s_waitcnt vmcnt(0)" ::: "memory");
        __syncthreads();   // (b) — all waves' h stores at L2
        if (tid == 0) {
            if constexpr (BAL)
                asm volatile("global_store_dword %0, %1, %2 sc0"
                             :: "v"(0), "v"(t + 1), "s"(sig64) : "memory");
            else
                __hip_atomic_store(flags + wgJ, t + 1, __ATOMIC_RELAXED,
                                   __HIP_MEMORY_SCOPE_AGENT);
        }

        // ---- output reduction tail (off the inter-WG critical path) ----
        #pragma unroll
        for (int k = 0; k < 4; ++k) {
            float v = pr[k];
            v += __shfl_xor(v, 1);
            v += __shfl_xor(v, 2);
            if (p == 0) outred[w * 64 + rl + 16 * k] = v;
        }
        __syncthreads();   // (d) — nothing outstanding, cheap
        if (tid < 64) {
            float s = outred[tid] + outred[64 + tid] + outred[128 + tid] + outred[192 + tid];
            if (OPart)
                OPart[((size_t)(t * 8 + bi) * 32 + wgJ) * 64 + tid] = s;
            else
                atomicAdd(out + (size_t)t * NGRID + bi * 64 + tid, s);
        }
    }
}

__global__ __launch_bounds__(256, 1)
void lstm_persist_kernel(const unsigned short* __restrict__ WPg,
                         const unsigned short* __restrict__ XMg,
                         unsigned int* __restrict__ hA,
                         unsigned int* __restrict__ hB,
                         const float* __restrict__ b_ih,
                         const float* __restrict__ b_hh,
                         const float* __restrict__ W_lin,
                         float* __restrict__ out,
                         float* __restrict__ OPart,
                         int* __restrict__ ctr)
{
    __shared__ i32x4 hsm4[4096];   // 64 KB
    __shared__ int setup_sh[3];
    const int tid = threadIdx.x;

    // one-time self-organization by physical XCD
    if (tid == 0) {
        uint32_t xcc;
        asm volatile("s_getreg_b32 %0, hwreg(HW_REG_XCC_ID)" : "=s"(xcc));
        xcc &= 7;
        int slot = __hip_atomic_fetch_add(&ctr[xcc], 1, __ATOMIC_RELAXED,
                                          __HIP_MEMORY_SCOPE_AGENT);
        asm volatile("s_waitcnt vmcnt(0)" ::: "memory");  // claim visible before arrive
        __hip_atomic_fetch_add(&ctr[8], 1, __ATOMIC_RELAXED,
                               __HIP_MEMORY_SCOPE_AGENT);
        while (__hip_atomic_load(&ctr[8], __ATOMIC_RELAXED,
                                 __HIP_MEMORY_SCOPE_AGENT) < 256)
            __builtin_amdgcn_s_sleep(1);
        int bal = 1;
        #pragma unroll
        for (int k = 0; k < 8; ++k)
            bal &= (__hip_atomic_load(&ctr[k], __ATOMIC_RELAXED,
                                      __HIP_MEMORY_SCOPE_AGENT) == 32);
        if (bal && slot < 32) {
            setup_sh[0] = 1; setup_sh[1] = (int)xcc; setup_sh[2] = slot;
        } else {
            setup_sh[0] = 0; setup_sh[1] = blockIdx.x & 7; setup_sh[2] = blockIdx.x >> 3;
        }
    }
    __syncthreads();
    const int bal = setup_sh[0];
    const int bi  = setup_sh[1];
    const int wgJ = setup_sh[2];
    int* flags = ctr + 256 + bi * 32;   // 128B line of 32 per-producer slots

    if (bal)
        lstm_loop<true>(tid, bi, wgJ, WPg, XMg, hA, hB, b_ih, b_hh, W_lin,
                        out, OPart, flags, hsm4);
    else
        lstm_loop<false>(tid, bi, wgJ, WPg, XMg, hA, hB, b_ih, b_hh, W_lin,
                         out, OPart, flags, hsm4);
}

// ---------------- launch ----------------
extern "C" void kernel_launch(void* const* d_in, const int* in_sizes, int n_in,
                              void* d_out, int out_size, void* d_ws, size_t ws_size,
                              hipStream_t stream)
{
    const float* x     = (const float*)d_in[0];
    const float* maskX = (const float*)d_in[1];
    const float* W_ih  = (const float*)d_in[2];
    const float* W_hh  = (const float*)d_in[3];
    const float* b_ih  = (const float*)d_in[4];
    const float* b_hh  = (const float*)d_in[5];
    const float* W_lin = (const float*)d_in[6];
    const float* b_lin = (const float*)d_in[7];
    float* out = (float*)d_out;

    char* ws = (char*)d_ws;
    const size_t WP_B  = 128ull * 80 * 512 * 2;          // 10,485,760
    const size_t XM_B  = (size_t)NT * 16384 * 8 * 2;     // 95,682,560
    const size_t H_B   = (size_t)NGRID * HID * 2;        // 1,048,576
    const size_t CTR_B = 4096;
    const size_t OP_B  = (size_t)NT * 8 * 32 * 64 * 4;   // 23,920,640

    unsigned short* WP = (unsigned short*)ws;
    unsigned short* XM = (unsigned short*)(ws + WP_B);
    unsigned int* hA   = (unsigned int*)(ws + WP_B + XM_B);
    unsigned int* hB   = (unsigned int*)(ws + WP_B + XM_B + H_B);
    int* ctr           = (int*)(ws + WP_B + XM_B + 2 * H_B);
    float* OPart       = (float*)(ws + WP_B + XM_B + 2 * H_B + CTR_B);

    const size_t need = WP_B + XM_B + 2 * H_B + CTR_B + OP_B;
    const bool use_part = (ws_size >= need);
    if (!use_part) OPart = nullptr;

    init_kernel<<<(NT * NGRID + 255) / 256, 256, 0, stream>>>(out, b_lin, ctr,
                                                              use_part ? 0 : 1);
    pack_w_kernel<<<(128 * 80 * 64 + 255) / 256, 256, 0, stream>>>(W_ih, W_hh, WP);
    size_t nxm = (size_t)NT * 16384;
    pack_xm_kernel<<<(int)((nxm + 255) / 256), 256, 0, stream>>>(x, maskX, XM);

    lstm_persist_kernel<<<256, 256, 0, stream>>>(WP, XM, hA, hB,
                                                 b_ih, b_hh, W_lin, out, OPart, ctr);
    if (use_part)
        reduce_out_kernel<<<(NT * NGRID + 255) / 256, 256, 0, stream>>>(OPart, b_lin, out);
}

// Round 5
// 8328.019 us; speedup vs baseline: 1.0248x; 1.0248x over previous
//
#include <hip/hip_runtime.h>
#include <hip/hip_bf16.h>
#include <stdint.h>

#define NT 365
#define NGRID 512
#define NX 256
#define HID 1024

typedef __bf16 bf16x8 __attribute__((ext_vector_type(8)));
typedef float f32x16 __attribute__((ext_vector_type(16)));
typedef float f32x4  __attribute__((ext_vector_type(4)));
typedef int   i32x4  __attribute__((ext_vector_type(4)));

__device__ __forceinline__ unsigned short f2bf(float f) {
    union { float f; uint32_t u; } v; v.f = f;
    uint32_t u = v.u;
    uint32_t r = (u + 0x7FFFu + ((u >> 16) & 1u)) >> 16;
    return (unsigned short)r;
}
__device__ __forceinline__ float sigmoidf_(float x) {
    return 1.0f / (1.0f + __expf(-x));
}
__device__ __forceinline__ float tanhf_(float x) {
    return 1.0f - 2.0f / (__expf(2.0f * x) + 1.0f);
}
__device__ __forceinline__ f32x16 mfma(bf16x8 a, bf16x8 b, f32x16 c) {
    return __builtin_amdgcn_mfma_f32_32x32x16_bf16(a, b, c, 0, 0, 0);
}

// ---------------- prep kernels ----------------

// WP[jg 0..127][kt 0..79][l 0..63][e 0..7] : B-frag order, gate-packed cols.
__global__ void pack_w_kernel(const float* __restrict__ W_ih,
                              const float* __restrict__ W_hh,
                              unsigned short* __restrict__ WP) {
    int tid = blockIdx.x * blockDim.x + threadIdx.x;
    if (tid >= 128 * 80 * 64) return;
    int l  = tid & 63;
    int kt = (tid >> 6) % 80;
    int jg = tid / (80 * 64);
    int n = l & 31;
    int gate = n & 3;
    int j = jg * 8 + (n >> 2);
    int k = kt * 16 + ((l >> 5) << 3);
    int row = gate * HID + j;
    const float* src = (k < HID) ? (W_hh + (size_t)row * HID + k)
                                 : (W_ih + (size_t)row * NX + (k - HID));
    unsigned short* dst = WP + (size_t)tid * 8;
    #pragma unroll
    for (int e = 0; e < 8; ++e) dst[e] = f2bf(src[e]);
}

// XM[t][bi][kt 0..15][a][l][e] : A-frag order of bf16(x * maskX).
__global__ void pack_xm_kernel(const float* __restrict__ x,
                               const float* __restrict__ maskX,
                               unsigned short* __restrict__ XM) {
    size_t tid = (size_t)blockIdx.x * blockDim.x + threadIdx.x;
    if (tid >= (size_t)NT * 16384) return;
    int l  = tid & 63;
    int a  = (tid >> 6) & 1;
    int kt = (tid >> 7) & 15;
    int bi = (tid >> 11) & 7;
    int t  = tid >> 14;
    int b = bi * 64 + a * 32 + (l & 31);
    int n = kt * 16 + ((l >> 5) << 3);
    const float* xs = x + ((size_t)t * NGRID + b) * NX + n;
    const float* ms = maskX + (size_t)b * NX + n;
    unsigned short* dst = XM + tid * 8;
    #pragma unroll
    for (int e = 0; e < 8; ++e) dst[e] = f2bf(xs[e] * ms[e]);
}

__global__ void init_kernel(float* __restrict__ out,
                            const float* __restrict__ b_lin,
                            int* __restrict__ ctr, int prefill) {
    int i = blockIdx.x * blockDim.x + threadIdx.x;
    if (i < 1024) ctr[i] = 0;
    if (prefill && i < NT * NGRID) out[i] = b_lin[0];
}

// final reduction: out[t,b] = b_lin + sum_wgJ OPart[t][bi][wgJ][bl]
__global__ void reduce_out_kernel(const float* __restrict__ OPart,
                                  const float* __restrict__ b_lin,
                                  float* __restrict__ out) {
    int i = blockIdx.x * blockDim.x + threadIdx.x;
    if (i >= NT * NGRID) return;
    int t = i >> 9, b = i & 511;
    int bi = b >> 6, bl = b & 63;
    const float* p = OPart + ((size_t)(t * 8 + bi) * 32) * 64 + bl;
    float s = b_lin[0];
    #pragma unroll
    for (int g = 0; g < 32; ++g) s += p[g * 64];
    out[i] = s;
}

// ---------------- persistent LSTM loop (templated on exchange scope) ----------------
// K-SPLIT (kept from round 4): wave pair (2p,2p+1) shares two col-slices; each
// wave computes BOTH slices over HALF of K -> every LDS A-read feeds 4 MFMAs.
// SPILL FIX (this round): round 4 spilled the 4 accumulators (VGPR peak ~260 >
// 256: acc 64 + staging 64 + temps, with wreg filling all 256 AGPRs). Fix:
// (1) single 32-reg staging buffer s0 with a rotated schedule (load latency of
// chunk c+1 still hides under mchunk(c)); (2) wregA/B pinned to AGPRs ("+a").
template<bool BAL>
__device__ void lstm_loop(int tid, int bi, int wgJ,
                          const unsigned short* __restrict__ WPg,
                          const unsigned short* __restrict__ XMg,
                          unsigned int* __restrict__ hA,
                          unsigned int* __restrict__ hB,
                          const float* __restrict__ b_ih,
                          const float* __restrict__ b_hh,
                          const float* __restrict__ W_lin,
                          float* __restrict__ out,
                          float* __restrict__ OPart,
                          int* __restrict__ flags,
                          i32x4* hsm4)
{
    const int w = tid >> 6;
    const int l = tid & 63;
    const int jg = wgJ * 4 + w;          // owned slice (post-merge)
    const int hk = w & 1;                // k-half of the pair
    const int sA = wgJ * 4 + (w & ~1);   // even slice of the pair

    float* exch = (float*)hsm4;                 // 4 x 2560 floats (overlay)
    float* outred = (float*)hsm4 + 10240;       // 256 floats (overlay)
    unsigned long long* hsm = (unsigned long long*)hsm4;

    // W resident in AGPRs: 2 slices x 32 kt (this wave's k-half) = 256 regs
    const bf16x8* __restrict__ WPvA = (const bf16x8*)WPg + (size_t)sA * 5120
                                      + (size_t)(hk * 32) * 64 + l;
    bf16x8 wregA[32], wregB[32];
    #pragma unroll
    for (int kt = 0; kt < 32; ++kt) {
        wregA[kt] = WPvA[kt * 64];
        wregB[kt] = WPvA[5120 + kt * 64];
    }
    #pragma unroll
    for (int kt = 0; kt < 32; ++kt) {
        asm volatile("" : "+a"(wregA[kt]));
        asm volatile("" : "+a"(wregB[kt]));
    }
    // xm-part B-frags (streamed from L2), split by hk: kt_local = hk*8 + [0..8)
    const bf16x8* __restrict__ WPxA = (const bf16x8*)WPg + (size_t)sA * 5120
                                      + (size_t)(64 + hk * 8) * 64 + l;

    const int c = l & 31;
    const int gate = c & 3;
    const int jcol = jg * 8 + (c >> 2);
    const float bias = b_ih[gate * HID + jcol] + b_hh[gate * HID + jcol];

    const int p = l & 3;
    const int rl = l >> 2;
    const float wl0 = W_lin[jg * 8 + 2 * p];
    const float wl1 = W_lin[jg * 8 + 2 * p + 1];

    const bf16x8* __restrict__ XMv = (const bf16x8*)XMg;
    const int voff = tid * 16;

    const uint64_t flags64 = (uint64_t)(uintptr_t)flags;
    const uint64_t sig64   = (uint64_t)(uintptr_t)(flags + wgJ);

    float creg[8];
    #pragma unroll
    for (int k = 0; k < 8; ++k) creg[k] = 0.0f;

    f32x16 aA0, aA1, aB0, aB1;

    auto issue = [&](i32x4* stg, uint64_t base) {
        #pragma unroll
        for (int ch = 0; ch < 8; ++ch)
            asm volatile("global_load_dwordx4 %0, %1, %2 sc0"
                         : "=v"(stg[ch])
                         : "v"(voff), "s"(base + (uint64_t)(ch * 4096)));
    };
    auto lwrite = [&](const i32x4* stg, int reg) {
        #pragma unroll
        for (int ch = 0; ch < 8; ++ch) hsm4[reg * 2048 + ch * 256 + tid] = stg[ch];
    };
    // chunk cn covers kt range [cn*16, cn*16+16); only waves with hk == cn>>1
    // consume it, computing BOTH slices (A-frag reused x2).
    auto mchunk = [&](int reg, int cn) {
        if ((cn >> 1) != hk) return;
        const int kb = (cn & 1) * 16;
        const bf16x8* hls = (const bf16x8*)(hsm4 + reg * 2048);
        #pragma unroll
        for (int kt = 0; kt < 16; ++kt) {
            bf16x8 a0 = hls[kt * 128 + l];
            bf16x8 a1 = hls[kt * 128 + 64 + l];
            aA0 = mfma(a0, wregA[kb + kt], aA0);
            aA1 = mfma(a1, wregA[kb + kt], aA1);
            aB0 = mfma(a0, wregB[kb + kt], aB0);
            aB1 = mfma(a1, wregB[kb + kt], aB1);
        }
    };

    #pragma unroll 1
    for (int t = 0; t < NT; ++t) {
        aA0 = (f32x16){}; aA1 = (f32x16){};
        aB0 = (f32x16){}; aB1 = (f32x16){};

        // ---- xm part (k-half hk): plain cached loads, independent of the flag ----
        const bf16x8* __restrict__ xp = XMv + (size_t)t * 16384 + bi * 2048
                                        + (hk * 8) * 128 + l;
        #pragma unroll
        for (int kt = 0; kt < 8; ++kt) {
            bf16x8 x0 = xp[kt * 128];
            bf16x8 x1 = xp[kt * 128 + 64];
            bf16x8 bA = WPxA[kt * 64];
            bf16x8 bB = WPxA[5120 + kt * 64];
            aA0 = mfma(x0, bA, aA0);
            aA1 = mfma(x1, bA, aA1);
            aB0 = mfma(x0, bB, aB0);
            aB1 = mfma(x1, bB, aB1);
        }

        // ---- wait for h(t-1): read-only per-slot poll, lane i watches slot i ----
        if (t > 0 && tid < 32) {
            if constexpr (BAL) {
                while (true) {
                    int v;
                    asm volatile("global_load_dword %0, %1, %2 sc0\n\t"
                                 "s_waitcnt vmcnt(0)"
                                 : "=v"(v)
                                 : "v"(tid * 4), "s"(flags64)
                                 : "memory");
                    if (v >= t) break;
                }
            } else {
                while (__hip_atomic_load(flags + tid, __ATOMIC_RELAXED,
                                         __HIP_MEMORY_SCOPE_AGENT) < t)
                    __builtin_amdgcn_s_sleep(2);
            }
        }
        __syncthreads();   // (c)

        if (t > 0) {
            __asm__ volatile("" ::: "memory");
            const char* hb = (const char*)((t & 1) ? hA : hB) + (size_t)bi * 131072;

            if constexpr (BAL) {
                uint64_t hb64 = (uint64_t)(uintptr_t)hb;
                i32x4 s0[8];                 // SINGLE staging buffer (32 VGPRs)
                issue(s0, hb64);             // c0
                asm volatile("s_waitcnt vmcnt(0)" ::: "memory");
                lwrite(s0, 0);
                issue(s0, hb64 + 32768);     // c1 (latency hides under mchunk c0)
                __syncthreads();             // S1: c0 visible in LDS0
                mchunk(0, 0);                // hk0 waves
                asm volatile("s_waitcnt vmcnt(0)" ::: "memory");   // c1 arrived
                lwrite(s0, 1);
                issue(s0, hb64 + 65536);     // c2
                __syncthreads();             // S2: c1 visible in LDS1
                mchunk(1, 1);                // hk0 waves
                asm volatile("s_waitcnt vmcnt(0)" ::: "memory");   // c2 arrived
                lwrite(s0, 0);
                issue(s0, hb64 + 98304);     // c3
                __syncthreads();             // S3: c2 visible in LDS0
                mchunk(0, 2);                // hk1 waves
                asm volatile("s_waitcnt vmcnt(0)" ::: "memory");   // c3 arrived
                lwrite(s0, 1);
                __syncthreads();             // S4: c3 visible in LDS1
                mchunk(1, 3);                // hk1 waves
                __syncthreads();             // S5: all reads done before merge overlay
            } else {
                const unsigned long long* __restrict__ hr =
                    (const unsigned long long*)hb + tid;
                unsigned long long stg[16];
                #pragma unroll
                for (int ch = 0; ch < 16; ++ch)
                    stg[ch] = __hip_atomic_load(hr + ch * 256, __ATOMIC_RELAXED,
                                                __HIP_MEMORY_SCOPE_AGENT);
                #pragma unroll
                for (int ch = 0; ch < 16; ++ch) hsm[ch * 256 + tid] = stg[ch];
                __syncthreads();
                #pragma unroll
                for (int ci = 0; ci < 4; ++ci) {
                    if (ci < 3) {
                        #pragma unroll
                        for (int ch = 0; ch < 16; ++ch)
                            stg[ch] = __hip_atomic_load(hr + (ci + 1) * 4096 + ch * 256,
                                                        __ATOMIC_RELAXED,
                                                        __HIP_MEMORY_SCOPE_AGENT);
                    }
                    mchunk(ci & 1, ci);
                    if (ci < 3) {
                        unsigned long long* __restrict__ dst = hsm + ((ci + 1) & 1) * 4096;
                        #pragma unroll
                        for (int ch = 0; ch < 16; ++ch) dst[ch * 256 + tid] = stg[ch];
                    }
                    __syncthreads();
                }
            }
        }

        // ---- merge k-halves within the wave pair (via 32 KB LDS overlay) ----
        f32x16 acc0, acc1;
        {
            i32x4* mg = hsm4;
            const int ps = (w ^ 1) * 512;   // partner's slot (they own what I write)
            if (hk) {   // I own slice B; hand over my slice-A partials
                #pragma unroll
                for (int q = 0; q < 4; ++q) {
                    mg[ps + q * 64 + l]       = ((i32x4*)&aA0)[q];
                    mg[ps + 256 + q * 64 + l] = ((i32x4*)&aA1)[q];
                }
            } else {    // I own slice A; hand over my slice-B partials
                #pragma unroll
                for (int q = 0; q < 4; ++q) {
                    mg[ps + q * 64 + l]       = ((i32x4*)&aB0)[q];
                    mg[ps + 256 + q * 64 + l] = ((i32x4*)&aB1)[q];
                }
            }
            __syncthreads();
            const int ms = w * 512;
            if (hk) {
                #pragma unroll
                for (int q = 0; q < 4; ++q) {
                    i32x4 v0 = mg[ms + q * 64 + l];
                    i32x4 v1 = mg[ms + 256 + q * 64 + l];
                    ((f32x4*)&aB0)[q] += *(const f32x4*)&v0;
                    ((f32x4*)&aB1)[q] += *(const f32x4*)&v1;
                }
                acc0 = aB0; acc1 = aB1;
            } else {
                #pragma unroll
                for (int q = 0; q < 4; ++q) {
                    i32x4 v0 = mg[ms + q * 64 + l];
                    i32x4 v1 = mg[ms + 256 + q * 64 + l];
                    ((f32x4*)&aA0)[q] += *(const f32x4*)&v0;
                    ((f32x4*)&aA1)[q] += *(const f32x4*)&v1;
                }
                acc0 = aA0; acc1 = aA1;
            }
            __syncthreads();   // slots free before exch overlay
        }

        // ---- gate transpose through per-wave LDS ----
        const int jj = c >> 2;
        const int wb = w * 2560;
        #pragma unroll
        for (int ri = 0; ri < 16; ++ri) {
            int r0 = (ri & 3) + 8 * (ri >> 2) + 4 * (l >> 5);
            exch[wb + (r0 * 8 + jj) * 5 + gate]        = acc0[ri] + bias;
            exch[wb + ((r0 + 32) * 8 + jj) * 5 + gate] = acc1[ri] + bias;
        }

        unsigned int* __restrict__ hw =
            ((t & 1) ? hB : hA) + (size_t)bi * 32768 + (jg >> 1) * 512 + p;
        float pr[4];
        #pragma unroll
        for (int k = 0; k < 4; ++k) {
            int r = rl + 16 * k;
            int f0 = wb + (r * 8 + 2 * p) * 5;
            float ia = sigmoidf_(exch[f0 + 0]);
            float fa = sigmoidf_(exch[f0 + 1]);
            float ga = tanhf_(exch[f0 + 2]);
            float oa = sigmoidf_(exch[f0 + 3]);
            float ib = sigmoidf_(exch[f0 + 5]);
            float fb = sigmoidf_(exch[f0 + 6]);
            float gb = tanhf_(exch[f0 + 7]);
            float ob = sigmoidf_(exch[f0 + 8]);
            float c0 = fa * creg[2 * k] + ia * ga;     creg[2 * k] = c0;
            float c1 = fb * creg[2 * k + 1] + ib * gb; creg[2 * k + 1] = c1;
            float h0 = oa * tanhf_(c0);
            float h1 = ob * tanhf_(c1);
            unsigned int pk = (unsigned int)f2bf(h0) | ((unsigned int)f2bf(h1) << 16);
            int a = r >> 5;
            int flane = ((jg & 1) << 5) | (r & 31);
            if constexpr (BAL)
                hw[a * 256 + flane * 4] = pk;          // write-through L1 -> XCD L2
            else
                __hip_atomic_store(&hw[a * 256 + flane * 4], pk, __ATOMIC_RELAXED,
                                   __HIP_MEMORY_SCOPE_AGENT);
            pr[k] = h0 * wl0 + h1 * wl1;
        }

        // drain h stores to the coherence point, then SIGNAL EARLY
        asm volatile("s_waitcnt vmcnt(0)" ::: "memory");
        __syncthreads();   // (b) — all waves' h stores at L2
        if (tid == 0) {
            if constexpr (BAL)
                asm volatile("global_store_dword %0, %1, %2 sc0"
                             :: "v"(0), "v"(t + 1), "s"(sig64) : "memory");
            else
                __hip_atomic_store(flags + wgJ, t + 1, __ATOMIC_RELAXED,
                                   __HIP_MEMORY_SCOPE_AGENT);
        }

        // ---- output reduction tail (off the inter-WG critical path) ----
        #pragma unroll
        for (int k = 0; k < 4; ++k) {
            float v = pr[k];
            v += __shfl_xor(v, 1);
            v += __shfl_xor(v, 2);
            if (p == 0) outred[w * 64 + rl + 16 * k] = v;
        }
        __syncthreads();   // (d) — nothing outstanding, cheap
        if (tid < 64) {
            float s = outred[tid] + outred[64 + tid] + outred[128 + tid] + outred[192 + tid];
            if (OPart)
                OPart[((size_t)(t * 8 + bi) * 32 + wgJ) * 64 + tid] = s;
            else
                atomicAdd(out + (size_t)t * NGRID + bi * 64 + tid, s);
        }
    }
}

__global__ __launch_bounds__(256, 1)
void lstm_persist_kernel(const unsigned short* __restrict__ WPg,
                         const unsigned short* __restrict__ XMg,
                         unsigned int* __restrict__ hA,
                         unsigned int* __restrict__ hB,
                         const float* __restrict__ b_ih,
                         const float* __restrict__ b_hh,
                         const float* __restrict__ W_lin,
                         float* __restrict__ out,
                         float* __restrict__ OPart,
                         int* __restrict__ ctr)
{
    __shared__ i32x4 hsm4[4096];   // 64 KB
    __shared__ int setup_sh[3];
    const int tid = threadIdx.x;

    // one-time self-organization by physical XCD
    if (tid == 0) {
        uint32_t xcc;
        asm volatile("s_getreg_b32 %0, hwreg(HW_REG_XCC_ID)" : "=s"(xcc));
        xcc &= 7;
        int slot = __hip_atomic_fetch_add(&ctr[xcc], 1, __ATOMIC_RELAXED,
                                          __HIP_MEMORY_SCOPE_AGENT);
        asm volatile("s_waitcnt vmcnt(0)" ::: "memory");  // claim visible before arrive
        __hip_atomic_fetch_add(&ctr[8], 1, __ATOMIC_RELAXED,
                               __HIP_MEMORY_SCOPE_AGENT);
        while (__hip_atomic_load(&ctr[8], __ATOMIC_RELAXED,
                                 __HIP_MEMORY_SCOPE_AGENT) < 256)
            __builtin_amdgcn_s_sleep(1);
        int bal = 1;
        #pragma unroll
        for (int k = 0; k < 8; ++k)
            bal &= (__hip_atomic_load(&ctr[k], __ATOMIC_RELAXED,
                                      __HIP_MEMORY_SCOPE_AGENT) == 32);
        if (bal && slot < 32) {
            setup_sh[0] = 1; setup_sh[1] = (int)xcc; setup_sh[2] = slot;
        } else {
            setup_sh[0] = 0; setup_sh[1] = blockIdx.x & 7; setup_sh[2] = blockIdx.x >> 3;
        }
    }
    __syncthreads();
    const int bal = setup_sh[0];
    const int bi  = setup_sh[1];
    const int wgJ = setup_sh[2];
    int* flags = ctr + 256 + bi * 32;   // 128B line of 32 per-producer slots

    if (bal)
        lstm_loop<true>(tid, bi, wgJ, WPg, XMg, hA, hB, b_ih, b_hh, W_lin,
                        out, OPart, flags, hsm4);
    else
        lstm_loop<false>(tid, bi, wgJ, WPg, XMg, hA, hB, b_ih, b_hh, W_lin,
                         out, OPart, flags, hsm4);
}

// ---------------- launch ----------------
extern "C" void kernel_launch(void* const* d_in, const int* in_sizes, int n_in,
                              void* d_out, int out_size, void* d_ws, size_t ws_size,
                              hipStream_t stream)
{
    const float* x     = (const float*)d_in[0];
    const float* maskX = (const float*)d_in[1];
    const float* W_ih  = (const float*)d_in[2];
    const float* W_hh  = (const float*)d_in[3];
    const float* b_ih  = (const float*)d_in[4];
    const float* b_hh  = (const float*)d_in[5];
    const float* W_lin = (const float*)d_in[6];
    const float* b_lin = (const float*)d_in[7];
    float* out = (float*)d_out;

    char* ws = (char*)d_ws;
    const size_t WP_B  = 128ull * 80 * 512 * 2;          // 10,485,760
    const size_t XM_B  = (size_t)NT * 16384 * 8 * 2;     // 95,682,560
    const size_t H_B   = (size_t)NGRID * HID * 2;        // 1,048,576
    const size_t CTR_B = 4096;
    const size_t OP_B  = (size_t)NT * 8 * 32 * 64 * 4;   // 23,920,640

    unsigned short* WP = (unsigned short*)ws;
    unsigned short* XM = (unsigned short*)(ws + WP_B);
    unsigned int* hA   = (unsigned int*)(ws + WP_B + XM_B);
    unsigned int* hB   = (unsigned int*)(ws + WP_B + XM_B + H_B);
    int* ctr           = (int*)(ws + WP_B + XM_B + 2 * H_B);
    float* OPart       = (float*)(ws + WP_B + XM_B + 2 * H_B + CTR_B);

    const size_t need = WP_B + XM_B + 2 * H_B + CTR_B + OP_B;
    const bool use_part = (ws_size >= need);
    if (!use_part) OPart = nullptr;

    init_kernel<<<(NT * NGRID + 255) / 256, 256, 0, stream>>>(out, b_lin, ctr,
                                                              use_part ? 0 : 1);
    pack_w_kernel<<<(128 * 80 * 64 + 255) / 256, 256, 0, stream>>>(W_ih, W_hh, WP);
    size_t nxm = (size_t)NT * 16384;
    pack_xm_kernel<<<(int)((nxm + 255) / 256), 256, 0, stream>>>(x, maskX, XM);

    lstm_persist_kernel<<<256, 256, 0, stream>>>(WP, XM, hA, hB,
                                                 b_ih, b_hh, W_lin, out, OPart, ctr);
    if (use_part)
        reduce_out_kernel<<<(NT * NGRID + 255) / 256, 256, 0, stream>>>(OPart, b_lin, out);
}

// Round 6
// 4828.595 us; speedup vs baseline: 1.7675x; 1.7247x over previous
//
#include <hip/hip_runtime.h>
#include <hip/hip_bf16.h>
#include <stdint.h>

#define NT 365
#define NGRID 512
#define NX 256
#define HID 1024

typedef __bf16 bf16x8 __attribute__((ext_vector_type(8)));
typedef float f32x16 __attribute__((ext_vector_type(16)));
typedef float f32x4  __attribute__((ext_vector_type(4)));
typedef int   i32x4  __attribute__((ext_vector_type(4)));

__device__ __forceinline__ unsigned short f2bf(float f) {
    union { float f; uint32_t u; } v; v.f = f;
    uint32_t u = v.u;
    uint32_t r = (u + 0x7FFFu + ((u >> 16) & 1u)) >> 16;
    return (unsigned short)r;
}
__device__ __forceinline__ float sigmoidf_(float x) {
    return 1.0f / (1.0f + __expf(-x));
}
__device__ __forceinline__ float tanhf_(float x) {
    return 1.0f - 2.0f / (__expf(2.0f * x) + 1.0f);
}
__device__ __forceinline__ f32x16 mfma(bf16x8 a, bf16x8 b, f32x16 c) {
    return __builtin_amdgcn_mfma_f32_32x32x16_bf16(a, b, c, 0, 0, 0);
}

// ---------------- prep kernels ----------------

// WP[jg 0..127][kt 0..79][l 0..63][e 0..7] : B-frag order, gate-packed cols.
__global__ void pack_w_kernel(const float* __restrict__ W_ih,
                              const float* __restrict__ W_hh,
                              unsigned short* __restrict__ WP) {
    int tid = blockIdx.x * blockDim.x + threadIdx.x;
    if (tid >= 128 * 80 * 64) return;
    int l  = tid & 63;
    int kt = (tid >> 6) % 80;
    int jg = tid / (80 * 64);
    int n = l & 31;
    int gate = n & 3;
    int j = jg * 8 + (n >> 2);
    int k = kt * 16 + ((l >> 5) << 3);
    int row = gate * HID + j;
    const float* src = (k < HID) ? (W_hh + (size_t)row * HID + k)
                                 : (W_ih + (size_t)row * NX + (k - HID));
    unsigned short* dst = WP + (size_t)tid * 8;
    #pragma unroll
    for (int e = 0; e < 8; ++e) dst[e] = f2bf(src[e]);
}

// XM[t][bi][kt 0..15][a][l][e] : A-frag order of bf16(x * maskX).
__global__ void pack_xm_kernel(const float* __restrict__ x,
                               const float* __restrict__ maskX,
                               unsigned short* __restrict__ XM) {
    size_t tid = (size_t)blockIdx.x * blockDim.x + threadIdx.x;
    if (tid >= (size_t)NT * 16384) return;
    int l  = tid & 63;
    int a  = (tid >> 6) & 1;
    int kt = (tid >> 7) & 15;
    int bi = (tid >> 11) & 7;
    int t  = tid >> 14;
    int b = bi * 64 + a * 32 + (l & 31);
    int n = kt * 16 + ((l >> 5) << 3);
    const float* xs = x + ((size_t)t * NGRID + b) * NX + n;
    const float* ms = maskX + (size_t)b * NX + n;
    unsigned short* dst = XM + tid * 8;
    #pragma unroll
    for (int e = 0; e < 8; ++e) dst[e] = f2bf(xs[e] * ms[e]);
}

__global__ void init_kernel(float* __restrict__ out,
                            const float* __restrict__ b_lin,
                            int* __restrict__ ctr, int prefill) {
    int i = blockIdx.x * blockDim.x + threadIdx.x;
    if (i < 1024) ctr[i] = 0;
    if (prefill && i < NT * NGRID) out[i] = b_lin[0];
}

// final reduction: out[t,b] = b_lin + sum_wgJ OPart[t][bi][wgJ][bl]
__global__ void reduce_out_kernel(const float* __restrict__ OPart,
                                  const float* __restrict__ b_lin,
                                  float* __restrict__ out) {
    int i = blockIdx.x * blockDim.x + threadIdx.x;
    if (i >= NT * NGRID) return;
    int t = i >> 9, b = i & 511;
    int bi = b >> 6, bl = b & 63;
    const float* p = OPart + ((size_t)(t * 8 + bi) * 32) * 64 + bl;
    float s = b_lin[0];
    #pragma unroll
    for (int g = 0; g < 32; ++g) s += p[g * 64];
    out[i] = s;
}

// ---------------- persistent LSTM loop (templated on exchange scope) ----------------
// K-SPLIT (kept): wave pair (2p,2p+1) shares two col-slices; each wave computes
// BOTH slices over HALF of K -> every LDS A-read feeds 4 MFMAs (A-read traffic
// halved: 512 -> 256 KB/step/CU).
// SPILL FIX (this round): rounds 4/5 took ADDRESSES of the f32x16 accumulators
// in the merge (((i32x4*)&aA0)[q]) -> allocator demoted all 4 accs to scratch
// (4.5-5.2 GB WRITE_SIZE). Merge is now pure element access (registers only);
// the "+a" pins are removed (no-op in r5).
template<bool BAL>
__device__ void lstm_loop(int tid, int bi, int wgJ,
                          const unsigned short* __restrict__ WPg,
                          const unsigned short* __restrict__ XMg,
                          unsigned int* __restrict__ hA,
                          unsigned int* __restrict__ hB,
                          const float* __restrict__ b_ih,
                          const float* __restrict__ b_hh,
                          const float* __restrict__ W_lin,
                          float* __restrict__ out,
                          float* __restrict__ OPart,
                          int* __restrict__ flags,
                          i32x4* hsm4)
{
    const int w = tid >> 6;
    const int l = tid & 63;
    const int jg = wgJ * 4 + w;          // owned slice (post-merge)
    const int hk = w & 1;                // k-half of the pair
    const int sA = wgJ * 4 + (w & ~1);   // even slice of the pair

    float* exch = (float*)hsm4;                 // 4 x 2560 floats (overlay)
    float* outred = (float*)hsm4 + 10240;       // 256 floats (overlay)
    unsigned long long* hsm = (unsigned long long*)hsm4;

    // W resident: 2 slices x 32 kt (this wave's k-half) = 64 frags = 256 regs
    const bf16x8* __restrict__ WPvA = (const bf16x8*)WPg + (size_t)sA * 5120
                                      + (size_t)(hk * 32) * 64 + l;
    bf16x8 wregA[32], wregB[32];
    #pragma unroll
    for (int kt = 0; kt < 32; ++kt) {
        wregA[kt] = WPvA[kt * 64];
        wregB[kt] = WPvA[5120 + kt * 64];
    }
    // xm-part B-frags (streamed from L2), split by hk: kt_local = hk*8 + [0..8)
    const bf16x8* __restrict__ WPxA = (const bf16x8*)WPg + (size_t)sA * 5120
                                      + (size_t)(64 + hk * 8) * 64 + l;

    const int c = l & 31;
    const int gate = c & 3;
    const int jcol = jg * 8 + (c >> 2);
    const float bias = b_ih[gate * HID + jcol] + b_hh[gate * HID + jcol];

    const int p = l & 3;
    const int rl = l >> 2;
    const float wl0 = W_lin[jg * 8 + 2 * p];
    const float wl1 = W_lin[jg * 8 + 2 * p + 1];

    const bf16x8* __restrict__ XMv = (const bf16x8*)XMg;
    const int voff = tid * 16;

    const uint64_t flags64 = (uint64_t)(uintptr_t)flags;
    const uint64_t sig64   = (uint64_t)(uintptr_t)(flags + wgJ);

    float creg[8];
    #pragma unroll
    for (int k = 0; k < 8; ++k) creg[k] = 0.0f;

    f32x16 aA0, aA1, aB0, aB1;

    auto issue = [&](i32x4* stg, uint64_t base) {
        #pragma unroll
        for (int ch = 0; ch < 8; ++ch)
            asm volatile("global_load_dwordx4 %0, %1, %2 sc0"
                         : "=v"(stg[ch])
                         : "v"(voff), "s"(base + (uint64_t)(ch * 4096)));
    };
    auto lwrite = [&](const i32x4* stg, int reg) {
        #pragma unroll
        for (int ch = 0; ch < 8; ++ch) hsm4[reg * 2048 + ch * 256 + tid] = stg[ch];
    };
    // chunk cn covers kt range [cn*16, cn*16+16); only waves with hk == cn>>1
    // consume it, computing BOTH slices (A-frag reused x2).
    auto mchunk = [&](int reg, int cn) {
        if ((cn >> 1) != hk) return;
        const int kb = (cn & 1) * 16;
        const bf16x8* hls = (const bf16x8*)(hsm4 + reg * 2048);
        #pragma unroll
        for (int kt = 0; kt < 16; ++kt) {
            bf16x8 a0 = hls[kt * 128 + l];
            bf16x8 a1 = hls[kt * 128 + 64 + l];
            aA0 = mfma(a0, wregA[kb + kt], aA0);
            aA1 = mfma(a1, wregA[kb + kt], aA1);
            aB0 = mfma(a0, wregB[kb + kt], aB0);
            aB1 = mfma(a1, wregB[kb + kt], aB1);
        }
    };

    #pragma unroll 1
    for (int t = 0; t < NT; ++t) {
        aA0 = (f32x16){}; aA1 = (f32x16){};
        aB0 = (f32x16){}; aB1 = (f32x16){};

        // ---- xm part (k-half hk): plain cached loads, independent of the flag ----
        const bf16x8* __restrict__ xp = XMv + (size_t)t * 16384 + bi * 2048
                                        + (hk * 8) * 128 + l;
        #pragma unroll
        for (int kt = 0; kt < 8; ++kt) {
            bf16x8 x0 = xp[kt * 128];
            bf16x8 x1 = xp[kt * 128 + 64];
            bf16x8 bA = WPxA[kt * 64];
            bf16x8 bB = WPxA[5120 + kt * 64];
            aA0 = mfma(x0, bA, aA0);
            aA1 = mfma(x1, bA, aA1);
            aB0 = mfma(x0, bB, aB0);
            aB1 = mfma(x1, bB, aB1);
        }

        // ---- wait for h(t-1): read-only per-slot poll, lane i watches slot i ----
        if (t > 0 && tid < 32) {
            if constexpr (BAL) {
                while (true) {
                    int v;
                    asm volatile("global_load_dword %0, %1, %2 sc0\n\t"
                                 "s_waitcnt vmcnt(0)"
                                 : "=v"(v)
                                 : "v"(tid * 4), "s"(flags64)
                                 : "memory");
                    if (v >= t) break;
                }
            } else {
                while (__hip_atomic_load(flags + tid, __ATOMIC_RELAXED,
                                         __HIP_MEMORY_SCOPE_AGENT) < t)
                    __builtin_amdgcn_s_sleep(2);
            }
        }
        __syncthreads();   // (c)

        if (t > 0) {
            __asm__ volatile("" ::: "memory");
            const char* hb = (const char*)((t & 1) ? hA : hB) + (size_t)bi * 131072;

            if constexpr (BAL) {
                uint64_t hb64 = (uint64_t)(uintptr_t)hb;
                i32x4 s0[8];                 // SINGLE staging buffer (32 VGPRs)
                issue(s0, hb64);             // c0
                asm volatile("s_waitcnt vmcnt(0)" ::: "memory");
                lwrite(s0, 0);
                issue(s0, hb64 + 32768);     // c1 (latency hides under mchunk c0)
                __syncthreads();             // S1: c0 visible in LDS0
                mchunk(0, 0);                // hk0 waves
                asm volatile("s_waitcnt vmcnt(0)" ::: "memory");   // c1 arrived
                lwrite(s0, 1);
                issue(s0, hb64 + 65536);     // c2
                __syncthreads();             // S2: c1 visible in LDS1
                mchunk(1, 1);                // hk0 waves
                asm volatile("s_waitcnt vmcnt(0)" ::: "memory");   // c2 arrived
                lwrite(s0, 0);
                issue(s0, hb64 + 98304);     // c3
                __syncthreads();             // S3: c2 visible in LDS0
                mchunk(0, 2);                // hk1 waves
                asm volatile("s_waitcnt vmcnt(0)" ::: "memory");   // c3 arrived
                lwrite(s0, 1);
                __syncthreads();             // S4: c3 visible in LDS1
                mchunk(1, 3);                // hk1 waves
                __syncthreads();             // S5: all reads done before merge overlay
            } else {
                const unsigned long long* __restrict__ hr =
                    (const unsigned long long*)hb + tid;
                unsigned long long stg[16];
                #pragma unroll
                for (int ch = 0; ch < 16; ++ch)
                    stg[ch] = __hip_atomic_load(hr + ch * 256, __ATOMIC_RELAXED,
                                                __HIP_MEMORY_SCOPE_AGENT);
                #pragma unroll
                for (int ch = 0; ch < 16; ++ch) hsm[ch * 256 + tid] = stg[ch];
                __syncthreads();
                #pragma unroll
                for (int ci = 0; ci < 4; ++ci) {
                    if (ci < 3) {
                        #pragma unroll
                        for (int ch = 0; ch < 16; ++ch)
                            stg[ch] = __hip_atomic_load(hr + (ci + 1) * 4096 + ch * 256,
                                                        __ATOMIC_RELAXED,
                                                        __HIP_MEMORY_SCOPE_AGENT);
                    }
                    mchunk(ci & 1, ci);
                    if (ci < 3) {
                        unsigned long long* __restrict__ dst = hsm + ((ci + 1) & 1) * 4096;
                        #pragma unroll
                        for (int ch = 0; ch < 16; ++ch) dst[ch * 256 + tid] = stg[ch];
                    }
                    __syncthreads();
                }
            }
        }

        // ---- merge k-halves within the wave pair (32 KB LDS overlay) ----
        // Pure element access: never take the address of a register vector.
        f32x16 acc0, acc1;
        {
            f32x4* mg4 = (f32x4*)hsm4;
            const int ps = (w ^ 1) * 512;   // partner's slot (they own what I write)
            if (hk) {   // I own slice B; hand over my slice-A partials
                #pragma unroll
                for (int q = 0; q < 4; ++q) {
                    f32x4 v0, v1;
                    #pragma unroll
                    for (int e = 0; e < 4; ++e) { v0[e] = aA0[4*q+e]; v1[e] = aA1[4*q+e]; }
                    mg4[ps + q * 64 + l]       = v0;
                    mg4[ps + 256 + q * 64 + l] = v1;
                }
            } else {    // I own slice A; hand over my slice-B partials
                #pragma unroll
                for (int q = 0; q < 4; ++q) {
                    f32x4 v0, v1;
                    #pragma unroll
                    for (int e = 0; e < 4; ++e) { v0[e] = aB0[4*q+e]; v1[e] = aB1[4*q+e]; }
                    mg4[ps + q * 64 + l]       = v0;
                    mg4[ps + 256 + q * 64 + l] = v1;
                }
            }
            __syncthreads();
            const int ms = w * 512;
            if (hk) {
                #pragma unroll
                for (int q = 0; q < 4; ++q) {
                    f32x4 u0 = mg4[ms + q * 64 + l];
                    f32x4 u1 = mg4[ms + 256 + q * 64 + l];
                    #pragma unroll
                    for (int e = 0; e < 4; ++e) { aB0[4*q+e] += u0[e]; aB1[4*q+e] += u1[e]; }
                }
                acc0 = aB0; acc1 = aB1;
            } else {
                #pragma unroll
                for (int q = 0; q < 4; ++q) {
                    f32x4 u0 = mg4[ms + q * 64 + l];
                    f32x4 u1 = mg4[ms + 256 + q * 64 + l];
                    #pragma unroll
                    for (int e = 0; e < 4; ++e) { aA0[4*q+e] += u0[e]; aA1[4*q+e] += u1[e]; }
                }
                acc0 = aA0; acc1 = aA1;
            }
            __syncthreads();   // slots free before exch overlay
        }

        // ---- gate transpose through per-wave LDS ----
        const int jj = c >> 2;
        const int wb = w * 2560;
        #pragma unroll
        for (int ri = 0; ri < 16; ++ri) {
            int r0 = (ri & 3) + 8 * (ri >> 2) + 4 * (l >> 5);
            exch[wb + (r0 * 8 + jj) * 5 + gate]        = acc0[ri] + bias;
            exch[wb + ((r0 + 32) * 8 + jj) * 5 + gate] = acc1[ri] + bias;
        }

        unsigned int* __restrict__ hw =
            ((t & 1) ? hB : hA) + (size_t)bi * 32768 + (jg >> 1) * 512 + p;
        float pr[4];
        #pragma unroll
        for (int k = 0; k < 4; ++k) {
            int r = rl + 16 * k;
            int f0 = wb + (r * 8 + 2 * p) * 5;
            float ia = sigmoidf_(exch[f0 + 0]);
            float fa = sigmoidf_(exch[f0 + 1]);
            float ga = tanhf_(exch[f0 + 2]);
            float oa = sigmoidf_(exch[f0 + 3]);
            float ib = sigmoidf_(exch[f0 + 5]);
            float fb = sigmoidf_(exch[f0 + 6]);
            float gb = tanhf_(exch[f0 + 7]);
            float ob = sigmoidf_(exch[f0 + 8]);
            float c0 = fa * creg[2 * k] + ia * ga;     creg[2 * k] = c0;
            float c1 = fb * creg[2 * k + 1] + ib * gb; creg[2 * k + 1] = c1;
            float h0 = oa * tanhf_(c0);
            float h1 = ob * tanhf_(c1);
            unsigned int pk = (unsigned int)f2bf(h0) | ((unsigned int)f2bf(h1) << 16);
            int a = r >> 5;
            int flane = ((jg & 1) << 5) | (r & 31);
            if constexpr (BAL)
                hw[a * 256 + flane * 4] = pk;          // write-through L1 -> XCD L2
            else
                __hip_atomic_store(&hw[a * 256 + flane * 4], pk, __ATOMIC_RELAXED,
                                   __HIP_MEMORY_SCOPE_AGENT);
            pr[k] = h0 * wl0 + h1 * wl1;
        }

        // drain h stores to the coherence point, then SIGNAL EARLY
        asm volatile("s_waitcnt vmcnt(0)" ::: "memory");
        __syncthreads();   // (b) — all waves' h stores at L2
        if (tid == 0) {
            if constexpr (BAL)
                asm volatile("global_store_dword %0, %1, %2 sc0"
                             :: "v"(0), "v"(t + 1), "s"(sig64) : "memory");
            else
                __hip_atomic_store(flags + wgJ, t + 1, __ATOMIC_RELAXED,
                                   __HIP_MEMORY_SCOPE_AGENT);
        }

        // ---- output reduction tail (off the inter-WG critical path) ----
        #pragma unroll
        for (int k = 0; k < 4; ++k) {
            float v = pr[k];
            v += __shfl_xor(v, 1);
            v += __shfl_xor(v, 2);
            if (p == 0) outred[w * 64 + rl + 16 * k] = v;
        }
        __syncthreads();   // (d) — nothing outstanding, cheap
        if (tid < 64) {
            float s = outred[tid] + outred[64 + tid] + outred[128 + tid] + outred[192 + tid];
            if (OPart)
                OPart[((size_t)(t * 8 + bi) * 32 + wgJ) * 64 + tid] = s;
            else
                atomicAdd(out + (size_t)t * NGRID + bi * 64 + tid, s);
        }
    }
}

__global__ __launch_bounds__(256, 1)
void lstm_persist_kernel(const unsigned short* __restrict__ WPg,
                         const unsigned short* __restrict__ XMg,
                         unsigned int* __restrict__ hA,
                         unsigned int* __restrict__ hB,
                         const float* __restrict__ b_ih,
                         const float* __restrict__ b_hh,
                         const float* __restrict__ W_lin,
                         float* __restrict__ out,
                         float* __restrict__ OPart,
                         int* __restrict__ ctr)
{
    __shared__ i32x4 hsm4[4096];   // 64 KB
    __shared__ int setup_sh[3];
    const int tid = threadIdx.x;

    // one-time self-organization by physical XCD
    if (tid == 0) {
        uint32_t xcc;
        asm volatile("s_getreg_b32 %0, hwreg(HW_REG_XCC_ID)" : "=s"(xcc));
        xcc &= 7;
        int slot = __hip_atomic_fetch_add(&ctr[xcc], 1, __ATOMIC_RELAXED,
                                          __HIP_MEMORY_SCOPE_AGENT);
        asm volatile("s_waitcnt vmcnt(0)" ::: "memory");  // claim visible before arrive
        __hip_atomic_fetch_add(&ctr[8], 1, __ATOMIC_RELAXED,
                               __HIP_MEMORY_SCOPE_AGENT);
        while (__hip_atomic_load(&ctr[8], __ATOMIC_RELAXED,
                                 __HIP_MEMORY_SCOPE_AGENT) < 256)
            __builtin_amdgcn_s_sleep(1);
        int bal = 1;
        #pragma unroll
        for (int k = 0; k < 8; ++k)
            bal &= (__hip_atomic_load(&ctr[k], __ATOMIC_RELAXED,
                                      __HIP_MEMORY_SCOPE_AGENT) == 32);
        if (bal && slot < 32) {
            setup_sh[0] = 1; setup_sh[1] = (int)xcc; setup_sh[2] = slot;
        } else {
            setup_sh[0] = 0; setup_sh[1] = blockIdx.x & 7; setup_sh[2] = blockIdx.x >> 3;
        }
    }
    __syncthreads();
    const int bal = setup_sh[0];
    const int bi  = setup_sh[1];
    const int wgJ = setup_sh[2];
    int* flags = ctr + 256 + bi * 32;   // 128B line of 32 per-producer slots

    if (bal)
        lstm_loop<true>(tid, bi, wgJ, WPg, XMg, hA, hB, b_ih, b_hh, W_lin,
                        out, OPart, flags, hsm4);
    else
        lstm_loop<false>(tid, bi, wgJ, WPg, XMg, hA, hB, b_ih, b_hh, W_lin,
                         out, OPart, flags, hsm4);
}

// ---------------- launch ----------------
extern "C" void kernel_launch(void* const* d_in, const int* in_sizes, int n_in,
                              void* d_out, int out_size, void* d_ws, size_t ws_size,
                              hipStream_t stream)
{
    const float* x     = (const float*)d_in[0];
    const float* maskX = (const float*)d_in[1];
    const float* W_ih  = (const float*)d_in[2];
    const float* W_hh  = (const float*)d_in[3];
    const float* b_ih  = (const float*)d_in[4];
    const float* b_hh  = (const float*)d_in[5];
    const float* W_lin = (const float*)d_in[6];
    const float* b_lin = (const float*)d_in[7];
    float* out = (float*)d_out;

    char* ws = (char*)d_ws;
    const size_t WP_B  = 128ull * 80 * 512 * 2;          // 10,485,760
    const size_t XM_B  = (size_t)NT * 16384 * 8 * 2;     // 95,682,560
    const size_t H_B   = (size_t)NGRID * HID * 2;        // 1,048,576
    const size_t CTR_B = 4096;
    const size_t OP_B  = (size_t)NT * 8 * 32 * 64 * 4;   // 23,920,640

    unsigned short* WP = (unsigned short*)ws;
    unsigned short* XM = (unsigned short*)(ws + WP_B);
    unsigned int* hA   = (unsigned int*)(ws + WP_B + XM_B);
    unsigned int* hB   = (unsigned int*)(ws + WP_B + XM_B + H_B);
    int* ctr           = (int*)(ws + WP_B + XM_B + 2 * H_B);
    float* OPart       = (float*)(ws + WP_B + XM_B + 2 * H_B + CTR_B);

    const size_t need = WP_B + XM_B + 2 * H_B + CTR_B + OP_B;
    const bool use_part = (ws_size >= need);
    if (!use_part) OPart = nullptr;

    init_kernel<<<(NT * NGRID + 255) / 256, 256, 0, stream>>>(out, b_lin, ctr,
                                                              use_part ? 0 : 1);
    pack_w_kernel<<<(128 * 80 * 64 + 255) / 256, 256, 0, stream>>>(W_ih, W_hh, WP);
    size_t nxm = (size_t)NT * 16384;
    pack_xm_kernel<<<(int)((nxm + 255) / 256), 256, 0, stream>>>(x, maskX, XM);

    lstm_persist_kernel<<<256, 256, 0, stream>>>(WP, XM, hA, hB,
                                                 b_ih, b_hh, W_lin, out, OPart, ctr);
    if (use_part)
        reduce_out_kernel<<<(NT * NGRID + 255) / 256, 256, 0, stream>>>(OPart, b_lin, out);
}

// Round 7
// 4034.033 us; speedup vs baseline: 2.1157x; 1.1970x over previous
//
#include <hip/hip_runtime.h>
#include <hip/hip_bf16.h>
#include <stdint.h>

#define NT 365
#define NGRID 512
#define NX 256
#define HID 1024

typedef __bf16 bf16x8 __attribute__((ext_vector_type(8)));
typedef float f32x16 __attribute__((ext_vector_type(16)));
typedef float f32x4  __attribute__((ext_vector_type(4)));
typedef int   i32x4  __attribute__((ext_vector_type(4)));

__device__ __forceinline__ unsigned short f2bf(float f) {
    union { float f; uint32_t u; } v; v.f = f;
    uint32_t u = v.u;
    uint32_t r = (u + 0x7FFFu + ((u >> 16) & 1u)) >> 16;
    return (unsigned short)r;
}
__device__ __forceinline__ float sigmoidf_(float x) {
    return 1.0f / (1.0f + __expf(-x));
}
__device__ __forceinline__ float tanhf_(float x) {
    return 1.0f - 2.0f / (__expf(2.0f * x) + 1.0f);
}
__device__ __forceinline__ f32x16 mfma(bf16x8 a, bf16x8 b, f32x16 c) {
    return __builtin_amdgcn_mfma_f32_32x32x16_bf16(a, b, c, 0, 0, 0);
}

// ---------------- prep kernels ----------------

// WP[jg 0..127][kt 0..79][l 0..63][e 0..7] : B-frag order, gate-packed cols.
__global__ void pack_w_kernel(const float* __restrict__ W_ih,
                              const float* __restrict__ W_hh,
                              unsigned short* __restrict__ WP) {
    int tid = blockIdx.x * blockDim.x + threadIdx.x;
    if (tid >= 128 * 80 * 64) return;
    int l  = tid & 63;
    int kt = (tid >> 6) % 80;
    int jg = tid / (80 * 64);
    int n = l & 31;
    int gate = n & 3;
    int j = jg * 8 + (n >> 2);
    int k = kt * 16 + ((l >> 5) << 3);
    int row = gate * HID + j;
    const float* src = (k < HID) ? (W_hh + (size_t)row * HID + k)
                                 : (W_ih + (size_t)row * NX + (k - HID));
    unsigned short* dst = WP + (size_t)tid * 8;
    #pragma unroll
    for (int e = 0; e < 8; ++e) dst[e] = f2bf(src[e]);
}

// XM[t][bi][kt 0..15][a][l][e] : A-frag order of bf16(x * maskX).
__global__ void pack_xm_kernel(const float* __restrict__ x,
                               const float* __restrict__ maskX,
                               unsigned short* __restrict__ XM) {
    size_t tid = (size_t)blockIdx.x * blockDim.x + threadIdx.x;
    if (tid >= (size_t)NT * 16384) return;
    int l  = tid & 63;
    int a  = (tid >> 6) & 1;
    int kt = (tid >> 7) & 15;
    int bi = (tid >> 11) & 7;
    int t  = tid >> 14;
    int b = bi * 64 + a * 32 + (l & 31);
    int n = kt * 16 + ((l >> 5) << 3);
    const float* xs = x + ((size_t)t * NGRID + b) * NX + n;
    const float* ms = maskX + (size_t)b * NX + n;
    unsigned short* dst = XM + tid * 8;
    #pragma unroll
    for (int e = 0; e < 8; ++e) dst[e] = f2bf(xs[e] * ms[e]);
}

__global__ void init_kernel(float* __restrict__ out,
                            const float* __restrict__ b_lin,
                            int* __restrict__ ctr, int prefill) {
    int i = blockIdx.x * blockDim.x + threadIdx.x;
    if (i < 1024) ctr[i] = 0;
    if (prefill && i < NT * NGRID) out[i] = b_lin[0];
}

// final reduction: out[t,b] = b_lin + sum_wgJ OPart[t][bi][wgJ][bl]
__global__ void reduce_out_kernel(const float* __restrict__ OPart,
                                  const float* __restrict__ b_lin,
                                  float* __restrict__ out) {
    int i = blockIdx.x * blockDim.x + threadIdx.x;
    if (i >= NT * NGRID) return;
    int t = i >> 9, b = i & 511;
    int bi = b >> 6, bl = b & 63;
    const float* p = OPart + ((size_t)(t * 8 + bi) * 32) * 64 + bl;
    float s = b_lin[0];
    #pragma unroll
    for (int g = 0; g < 32; ++g) s += p[g * 64];
    out[i] = s;
}

// ---------------- persistent LSTM loop (templated on exchange scope) ----------------
// K-SPLIT (kept): wave pair shares two col-slices; each wave computes BOTH over
// half of K -> each LDS A-read feeds 4 MFMAs.
// NEW this round (BAL path): h-exchange restructured from 4 serial
// {wait+lwrite+barrier+half-idle-mchunk} phases into ONE DMA load phase + ONE
// concurrent compute phase:
//   - LDS grown to 128 KB (dynamic): 4 x 32 KB chunk buffers.
//   - wave w issues global_load_lds (width 16, sc0) for chunk w: no staging
//     VGPRs, no lwrite VALU/LDS stores, loads go straight to LDS.
//   - single vmcnt(0)+barrier, then hk0 waves compute chunks 0,1 CONCURRENTLY
//     with hk1 waves computing chunks 2,3 (different SIMDs, different buffers).
//   h-MFMA serial time 2048->1024 cy; 3 of 4 exposed load-waits removed.
template<bool BAL>
__device__ void lstm_loop(int tid, int bi, int wgJ,
                          const unsigned short* __restrict__ WPg,
                          const unsigned short* __restrict__ XMg,
                          unsigned int* __restrict__ hA,
                          unsigned int* __restrict__ hB,
                          const float* __restrict__ b_ih,
                          const float* __restrict__ b_hh,
                          const float* __restrict__ W_lin,
                          float* __restrict__ out,
                          float* __restrict__ OPart,
                          int* __restrict__ flags,
                          i32x4* hsm4)
{
    const int w = tid >> 6;
    const int l = tid & 63;
    const int jg = wgJ * 4 + w;          // owned slice (post-merge)
    const int hk = w & 1;                // k-half of the pair
    const int sA = wgJ * 4 + (w & ~1);   // even slice of the pair

    float* exch = (float*)hsm4;                 // 4 x 2560 floats (overlay)
    float* outred = (float*)hsm4 + 10240;       // 256 floats (overlay)
    unsigned long long* hsm = (unsigned long long*)hsm4;

    // W resident: 2 slices x 32 kt (this wave's k-half) = 64 frags = 256 regs
    const bf16x8* __restrict__ WPvA = (const bf16x8*)WPg + (size_t)sA * 5120
                                      + (size_t)(hk * 32) * 64 + l;
    bf16x8 wregA[32], wregB[32];
    #pragma unroll
    for (int kt = 0; kt < 32; ++kt) {
        wregA[kt] = WPvA[kt * 64];
        wregB[kt] = WPvA[5120 + kt * 64];
    }
    // xm-part B-frags (streamed from L2), split by hk: kt_local = hk*8 + [0..8)
    const bf16x8* __restrict__ WPxA = (const bf16x8*)WPg + (size_t)sA * 5120
                                      + (size_t)(64 + hk * 8) * 64 + l;

    const int c = l & 31;
    const int gate = c & 3;
    const int jcol = jg * 8 + (c >> 2);
    const float bias = b_ih[gate * HID + jcol] + b_hh[gate * HID + jcol];

    const int p = l & 3;
    const int rl = l >> 2;
    const float wl0 = W_lin[jg * 8 + 2 * p];
    const float wl1 = W_lin[jg * 8 + 2 * p + 1];

    const bf16x8* __restrict__ XMv = (const bf16x8*)XMg;

    const uint64_t flags64 = (uint64_t)(uintptr_t)flags;
    const uint64_t sig64   = (uint64_t)(uintptr_t)(flags + wgJ);

    float creg[8];
    #pragma unroll
    for (int k = 0; k < 8; ++k) creg[k] = 0.0f;

    f32x16 aA0, aA1, aB0, aB1;

    // chunk cn covers kt range [cn*16, cn*16+16); only waves with hk == cn>>1
    // consume it, computing BOTH slices (A-frag reused x2). reg = LDS buffer idx.
    auto mchunk = [&](int reg, int cn) {
        if ((cn >> 1) != hk) return;
        const int kb = (cn & 1) * 16;
        const bf16x8* hls = (const bf16x8*)(hsm4 + reg * 2048);
        #pragma unroll
        for (int kt = 0; kt < 16; ++kt) {
            bf16x8 a0 = hls[kt * 128 + l];
            bf16x8 a1 = hls[kt * 128 + 64 + l];
            aA0 = mfma(a0, wregA[kb + kt], aA0);
            aA1 = mfma(a1, wregA[kb + kt], aA1);
            aB0 = mfma(a0, wregB[kb + kt], aB0);
            aB1 = mfma(a1, wregB[kb + kt], aB1);
        }
    };

    #pragma unroll 1
    for (int t = 0; t < NT; ++t) {
        aA0 = (f32x16){}; aA1 = (f32x16){};
        aB0 = (f32x16){}; aB1 = (f32x16){};

        // ---- xm part (k-half hk): plain cached loads, independent of the flag ----
        const bf16x8* __restrict__ xp = XMv + (size_t)t * 16384 + bi * 2048
                                        + (hk * 8) * 128 + l;
        #pragma unroll
        for (int kt = 0; kt < 8; ++kt) {
            bf16x8 x0 = xp[kt * 128];
            bf16x8 x1 = xp[kt * 128 + 64];
            bf16x8 bA = WPxA[kt * 64];
            bf16x8 bB = WPxA[5120 + kt * 64];
            aA0 = mfma(x0, bA, aA0);
            aA1 = mfma(x1, bA, aA1);
            aB0 = mfma(x0, bB, aB0);
            aB1 = mfma(x1, bB, aB1);
        }

        // ---- wait for h(t-1): read-only per-slot poll, lane i watches slot i ----
        if (t > 0 && tid < 32) {
            if constexpr (BAL) {
                while (true) {
                    int v;
                    asm volatile("global_load_dword %0, %1, %2 sc0\n\t"
                                 "s_waitcnt vmcnt(0)"
                                 : "=v"(v)
                                 : "v"(tid * 4), "s"(flags64)
                                 : "memory");
                    if (v >= t) break;
                }
            } else {
                while (__hip_atomic_load(flags + tid, __ATOMIC_RELAXED,
                                         __HIP_MEMORY_SCOPE_AGENT) < t)
                    __builtin_amdgcn_s_sleep(2);
            }
        }
        __syncthreads();   // (c)

        if (t > 0) {
            __asm__ volatile("" ::: "memory");
            const char* hb = (const char*)((t & 1) ? hA : hB) + (size_t)bi * 131072;

            if constexpr (BAL) {
                // wave w DMA-loads chunk w (32 KB) straight into LDS buffer w.
                // dest = wave-uniform base + lane*16 (linear) as required.
                const char* src = hb + (size_t)w * 32768 + (size_t)l * 16;
                char* dst = (char*)hsm4 + (size_t)w * 32768 + (size_t)l * 16;
                #pragma unroll
                for (int ch = 0; ch < 32; ++ch)
                    __builtin_amdgcn_global_load_lds(
                        (const __attribute__((address_space(1))) void*)(src + ch * 1024),
                        (__attribute__((address_space(3))) void*)(dst + ch * 1024),
                        16, 0, 1 /*sc0: bypass possibly-stale L1*/);
                asm volatile("s_waitcnt vmcnt(0)" ::: "memory");
                __syncthreads();              // all 4 chunks resident
                // concurrent: hk0 waves -> chunks 0,1 ; hk1 waves -> chunks 2,3
                mchunk(2 * hk + 0, 2 * hk + 0);
                mchunk(2 * hk + 1, 2 * hk + 1);
                __syncthreads();              // all reads done before merge overlay
            } else {
                const unsigned long long* __restrict__ hr =
                    (const unsigned long long*)hb + tid;
                unsigned long long stg[16];
                #pragma unroll
                for (int ch = 0; ch < 16; ++ch)
                    stg[ch] = __hip_atomic_load(hr + ch * 256, __ATOMIC_RELAXED,
                                                __HIP_MEMORY_SCOPE_AGENT);
                #pragma unroll
                for (int ch = 0; ch < 16; ++ch) hsm[ch * 256 + tid] = stg[ch];
                __syncthreads();
                #pragma unroll
                for (int ci = 0; ci < 4; ++ci) {
                    if (ci < 3) {
                        #pragma unroll
                        for (int ch = 0; ch < 16; ++ch)
                            stg[ch] = __hip_atomic_load(hr + (ci + 1) * 4096 + ch * 256,
                                                        __ATOMIC_RELAXED,
                                                        __HIP_MEMORY_SCOPE_AGENT);
                    }
                    mchunk(ci & 1, ci);
                    if (ci < 3) {
                        unsigned long long* __restrict__ dst = hsm + ((ci + 1) & 1) * 4096;
                        #pragma unroll
                        for (int ch = 0; ch < 16; ++ch) dst[ch * 256 + tid] = stg[ch];
                    }
                    __syncthreads();
                }
            }
        }

        // ---- merge k-halves within the wave pair (32 KB LDS overlay) ----
        // Pure element access: never take the address of a register vector.
        f32x16 acc0, acc1;
        {
            f32x4* mg4 = (f32x4*)hsm4;
            const int ps = (w ^ 1) * 512;   // partner's slot (they own what I write)
            if (hk) {   // I own slice B; hand over my slice-A partials
                #pragma unroll
                for (int q = 0; q < 4; ++q) {
                    f32x4 v0, v1;
                    #pragma unroll
                    for (int e = 0; e < 4; ++e) { v0[e] = aA0[4*q+e]; v1[e] = aA1[4*q+e]; }
                    mg4[ps + q * 64 + l]       = v0;
                    mg4[ps + 256 + q * 64 + l] = v1;
                }
            } else {    // I own slice A; hand over my slice-B partials
                #pragma unroll
                for (int q = 0; q < 4; ++q) {
                    f32x4 v0, v1;
                    #pragma unroll
                    for (int e = 0; e < 4; ++e) { v0[e] = aB0[4*q+e]; v1[e] = aB1[4*q+e]; }
                    mg4[ps + q * 64 + l]       = v0;
                    mg4[ps + 256 + q * 64 + l] = v1;
                }
            }
            __syncthreads();
            const int ms = w * 512;
            if (hk) {
                #pragma unroll
                for (int q = 0; q < 4; ++q) {
                    f32x4 u0 = mg4[ms + q * 64 + l];
                    f32x4 u1 = mg4[ms + 256 + q * 64 + l];
                    #pragma unroll
                    for (int e = 0; e < 4; ++e) { aB0[4*q+e] += u0[e]; aB1[4*q+e] += u1[e]; }
                }
                acc0 = aB0; acc1 = aB1;
            } else {
                #pragma unroll
                for (int q = 0; q < 4; ++q) {
                    f32x4 u0 = mg4[ms + q * 64 + l];
                    f32x4 u1 = mg4[ms + 256 + q * 64 + l];
                    #pragma unroll
                    for (int e = 0; e < 4; ++e) { aA0[4*q+e] += u0[e]; aA1[4*q+e] += u1[e]; }
                }
                acc0 = aA0; acc1 = aA1;
            }
            __syncthreads();   // slots free before exch overlay
        }

        // ---- gate transpose through per-wave LDS ----
        const int jj = c >> 2;
        const int wb = w * 2560;
        #pragma unroll
        for (int ri = 0; ri < 16; ++ri) {
            int r0 = (ri & 3) + 8 * (ri >> 2) + 4 * (l >> 5);
            exch[wb + (r0 * 8 + jj) * 5 + gate]        = acc0[ri] + bias;
            exch[wb + ((r0 + 32) * 8 + jj) * 5 + gate] = acc1[ri] + bias;
        }

        unsigned int* __restrict__ hw =
            ((t & 1) ? hB : hA) + (size_t)bi * 32768 + (jg >> 1) * 512 + p;
        float pr[4];
        #pragma unroll
        for (int k = 0; k < 4; ++k) {
            int r = rl + 16 * k;
            int f0 = wb + (r * 8 + 2 * p) * 5;
            float ia = sigmoidf_(exch[f0 + 0]);
            float fa = sigmoidf_(exch[f0 + 1]);
            float ga = tanhf_(exch[f0 + 2]);
            float oa = sigmoidf_(exch[f0 + 3]);
            float ib = sigmoidf_(exch[f0 + 5]);
            float fb = sigmoidf_(exch[f0 + 6]);
            float gb = tanhf_(exch[f0 + 7]);
            float ob = sigmoidf_(exch[f0 + 8]);
            float c0 = fa * creg[2 * k] + ia * ga;     creg[2 * k] = c0;
            float c1 = fb * creg[2 * k + 1] + ib * gb; creg[2 * k + 1] = c1;
            float h0 = oa * tanhf_(c0);
            float h1 = ob * tanhf_(c1);
            unsigned int pk = (unsigned int)f2bf(h0) | ((unsigned int)f2bf(h1) << 16);
            int a = r >> 5;
            int flane = ((jg & 1) << 5) | (r & 31);
            if constexpr (BAL)
                hw[a * 256 + flane * 4] = pk;          // write-through L1 -> XCD L2
            else
                __hip_atomic_store(&hw[a * 256 + flane * 4], pk, __ATOMIC_RELAXED,
                                   __HIP_MEMORY_SCOPE_AGENT);
            pr[k] = h0 * wl0 + h1 * wl1;
        }

        // drain h stores to the coherence point, then SIGNAL EARLY
        asm volatile("s_waitcnt vmcnt(0)" ::: "memory");
        __syncthreads();   // (b) — all waves' h stores at L2
        if (tid == 0) {
            if constexpr (BAL)
                asm volatile("global_store_dword %0, %1, %2 sc0"
                             :: "v"(0), "v"(t + 1), "s"(sig64) : "memory");
            else
                __hip_atomic_store(flags + wgJ, t + 1, __ATOMIC_RELAXED,
                                   __HIP_MEMORY_SCOPE_AGENT);
        }

        // ---- output reduction tail (off the inter-WG critical path) ----
        #pragma unroll
        for (int k = 0; k < 4; ++k) {
            float v = pr[k];
            v += __shfl_xor(v, 1);
            v += __shfl_xor(v, 2);
            if (p == 0) outred[w * 64 + rl + 16 * k] = v;
        }
        __syncthreads();   // (d) — nothing outstanding, cheap
        if (tid < 64) {
            float s = outred[tid] + outred[64 + tid] + outred[128 + tid] + outred[192 + tid];
            if (OPart)
                OPart[((size_t)(t * 8 + bi) * 32 + wgJ) * 64 + tid] = s;
            else
                atomicAdd(out + (size_t)t * NGRID + bi * 64 + tid, s);
        }
    }
}

__global__ __launch_bounds__(256, 1)
void lstm_persist_kernel(const unsigned short* __restrict__ WPg,
                         const unsigned short* __restrict__ XMg,
                         unsigned int* __restrict__ hA,
                         unsigned int* __restrict__ hB,
                         const float* __restrict__ b_ih,
                         const float* __restrict__ b_hh,
                         const float* __restrict__ W_lin,
                         float* __restrict__ out,
                         float* __restrict__ OPart,
                         int* __restrict__ ctr)
{
    extern __shared__ i32x4 hsm4[];   // 128 KB dynamic: 4 x 32 KB chunk buffers
    __shared__ int setup_sh[3];
    const int tid = threadIdx.x;

    // one-time self-organization by physical XCD
    if (tid == 0) {
        uint32_t xcc;
        asm volatile("s_getreg_b32 %0, hwreg(HW_REG_XCC_ID)" : "=s"(xcc));
        xcc &= 7;
        int slot = __hip_atomic_fetch_add(&ctr[xcc], 1, __ATOMIC_RELAXED,
                                          __HIP_MEMORY_SCOPE_AGENT);
        asm volatile("s_waitcnt vmcnt(0)" ::: "memory");  // claim visible before arrive
        __hip_atomic_fetch_add(&ctr[8], 1, __ATOMIC_RELAXED,
                               __HIP_MEMORY_SCOPE_AGENT);
        while (__hip_atomic_load(&ctr[8], __ATOMIC_RELAXED,
                                 __HIP_MEMORY_SCOPE_AGENT) < 256)
            __builtin_amdgcn_s_sleep(1);
        int bal = 1;
        #pragma unroll
        for (int k = 0; k < 8; ++k)
            bal &= (__hip_atomic_load(&ctr[k], __ATOMIC_RELAXED,
                                      __HIP_MEMORY_SCOPE_AGENT) == 32);
        if (bal && slot < 32) {
            setup_sh[0] = 1; setup_sh[1] = (int)xcc; setup_sh[2] = slot;
        } else {
            setup_sh[0] = 0; setup_sh[1] = blockIdx.x & 7; setup_sh[2] = blockIdx.x >> 3;
        }
    }
    __syncthreads();
    const int bal = setup_sh[0];
    const int bi  = setup_sh[1];
    const int wgJ = setup_sh[2];
    int* flags = ctr + 256 + bi * 32;   // 128B line of 32 per-producer slots

    if (bal)
        lstm_loop<true>(tid, bi, wgJ, WPg, XMg, hA, hB, b_ih, b_hh, W_lin,
                        out, OPart, flags, hsm4);
    else
        lstm_loop<false>(tid, bi, wgJ, WPg, XMg, hA, hB, b_ih, b_hh, W_lin,
                         out, OPart, flags, hsm4);
}

// ---------------- launch ----------------
extern "C" void kernel_launch(void* const* d_in, const int* in_sizes, int n_in,
                              void* d_out, int out_size, void* d_ws, size_t ws_size,
                              hipStream_t stream)
{
    const float* x     = (const float*)d_in[0];
    const float* maskX = (const float*)d_in[1];
    const float* W_ih  = (const float*)d_in[2];
    const float* W_hh  = (const float*)d_in[3];
    const float* b_ih  = (const float*)d_in[4];
    const float* b_hh  = (const float*)d_in[5];
    const float* W_lin = (const float*)d_in[6];
    const float* b_lin = (const float*)d_in[7];
    float* out = (float*)d_out;

    char* ws = (char*)d_ws;
    const size_t WP_B  = 128ull * 80 * 512 * 2;          // 10,485,760
    const size_t XM_B  = (size_t)NT * 16384 * 8 * 2;     // 95,682,560
    const size_t H_B   = (size_t)NGRID * HID * 2;        // 1,048,576
    const size_t CTR_B = 4096;
    const size_t OP_B  = (size_t)NT * 8 * 32 * 64 * 4;   // 23,920,640

    unsigned short* WP = (unsigned short*)ws;
    unsigned short* XM = (unsigned short*)(ws + WP_B);
    unsigned int* hA   = (unsigned int*)(ws + WP_B + XM_B);
    unsigned int* hB   = (unsigned int*)(ws + WP_B + XM_B + H_B);
    int* ctr           = (int*)(ws + WP_B + XM_B + 2 * H_B);
    float* OPart       = (float*)(ws + WP_B + XM_B + 2 * H_B + CTR_B);

    const size_t need = WP_B + XM_B + 2 * H_B + CTR_B + OP_B;
    const bool use_part = (ws_size >= need);
    if (!use_part) OPart = nullptr;

    // allow 128 KB dynamic LDS for the persistent kernel (idempotent)
    (void)hipFuncSetAttribute((const void*)lstm_persist_kernel,
                              hipFuncAttributeMaxDynamicSharedMemorySize, 131072);

    init_kernel<<<(NT * NGRID + 255) / 256, 256, 0, stream>>>(out, b_lin, ctr,
                                                              use_part ? 0 : 1);
    pack_w_kernel<<<(128 * 80 * 64 + 255) / 256, 256, 0, stream>>>(W_ih, W_hh, WP);
    size_t nxm = (size_t)NT * 16384;
    pack_xm_kernel<<<(int)((nxm + 255) / 256), 256, 0, stream>>>(x, maskX, XM);

    lstm_persist_kernel<<<256, 256, 131072, stream>>>(WP, XM, hA, hB,
                                                      b_ih, b_hh, W_lin, out, OPart, ctr);
    if (use_part)
        reduce_out_kernel<<<(NT * NGRID + 255) / 256, 256, 0, stream>>>(OPart, b_lin, out);
}